// Round 11
// baseline (597.283 us; speedup 1.0000x reference)
//
#include <hip/hip_runtime.h>
#include <hip/hip_bf16.h>

#define BB 16
#define NN 10
#define CC 128
#define HWD 2304            // 48*48
#define DD (CC*HWD)         // 294912
#define NC (NN*CC)          // 1280

#define CH2 72              // chunks per b for dot kernel
#define CHUNK2 4096         // floats per chunk

#define BM 128
#define BN 128
#define BK 32
#define TK (NC/BK)          // 40 K-steps

typedef __bf16 bf16x8 __attribute__((ext_vector_type(8)));
typedef float  f32x4  __attribute__((ext_vector_type(4)));

#define FEAT_BYTES ((size_t)BB*HWD*NC*2)     // 94,371,840
#define WB_BYTES   ((size_t)NC*NC*2)         // 3,276,800
#define PART_FLOATS (BB*NN*CH2*3)            // 34,560

__device__ __forceinline__ ushort f2bf(float f) {
    __hip_bfloat16 h = __float2bfloat16(f);
    return *reinterpret_cast<ushort*>(&h);
}

// ---------------- Kernel 1: dots d0,d1,d2 — single pass over x ----------------
__global__ __launch_bounds__(256) void k_dots(const float* __restrict__ x,
                                              float* __restrict__ part) {
    int blk = blockIdx.x;             // 0..BB*CH2-1
    int ch = blk % CH2;
    int b  = blk / CH2;
    const float* base = x + (size_t)b*NN*DD + (size_t)ch*CHUNK2;
    int t = threadIdx.x;

    float4 cur[4], nxt[4], inc[4];
    #pragma unroll
    for (int i = 0; i < 4; ++i) cur[i] = *(const float4*)(base + (size_t)0*DD + i*1024 + t*4);
    #pragma unroll
    for (int i = 0; i < 4; ++i) nxt[i] = *(const float4*)(base + (size_t)1*DD + i*1024 + t*4);

    __shared__ float red[4][3];
    int w = t >> 6, l = t & 63;

    for (int n = 0; n < NN; ++n) {
        int n2 = (n + 2) % NN;
        #pragma unroll
        for (int i = 0; i < 4; ++i) inc[i] = *(const float4*)(base + (size_t)n2*DD + i*1024 + t*4);

        float s0 = 0.f, s1 = 0.f, s2 = 0.f;
        #pragma unroll
        for (int i = 0; i < 4; ++i) {
            s0 += cur[i].x*cur[i].x + cur[i].y*cur[i].y + cur[i].z*cur[i].z + cur[i].w*cur[i].w;
            s1 += cur[i].x*nxt[i].x + cur[i].y*nxt[i].y + cur[i].z*nxt[i].z + cur[i].w*nxt[i].w;
            s2 += cur[i].x*inc[i].x + cur[i].y*inc[i].y + cur[i].z*inc[i].z + cur[i].w*inc[i].w;
        }
        for (int o = 32; o > 0; o >>= 1) {
            s0 += __shfl_down(s0, o);
            s1 += __shfl_down(s1, o);
            s2 += __shfl_down(s2, o);
        }
        if (l == 0) { red[w][0] = s0; red[w][1] = s1; red[w][2] = s2; }
        __syncthreads();
        if (t == 0) {
            float r0 = 0.f, r1 = 0.f, r2 = 0.f;
            #pragma unroll
            for (int i = 0; i < 4; ++i) { r0 += red[i][0]; r1 += red[i][1]; r2 += red[i][2]; }
            float* o = part + ((size_t)(b*NN + n)*CH2 + ch)*3;
            o[0] = r0; o[1] = r1; o[2] = r2;
        }
        __syncthreads();
        #pragma unroll
        for (int i = 0; i < 4; ++i) { cur[i] = nxt[i]; nxt[i] = inc[i]; }
    }
}

// ---------------- Kernel 2: softmax -> combination coefficients ----------------
__global__ void k_coef(const float* __restrict__ part,
                       const float* __restrict__ pos_dec,
                       const float* __restrict__ len_dec,
                       float* __restrict__ coef) {
    int bn = threadIdx.x;
    if (bn >= BB*NN) return;
    int n = bn % NN;
    float d0 = 0.f, d1 = 0.f, d2 = 0.f;
    const float* p = part + (size_t)bn*CH2*3;
    for (int i = 0; i < CH2; ++i) { d0 += p[i*3]; d1 += p[i*3+1]; d2 += p[i*3+2]; }
    float pd = pos_dec[n], ld = len_dec[n];
    float l0 = (1.f - pd)*d0 + pd*d1;
    float l1 = ld*((1.f - pd)*d1 + pd*d2);
    float m  = fmaxf(l0, l1);
    float e0 = expf(l0 - m), e1 = expf(l1 - m);
    float inv = 1.f/(e0 + e1);
    float a0 = e0*inv, a1 = e1*inv;
    coef[bn*3+0] = a0*(1.f - pd);
    coef[bn*3+1] = a0*pd + a1*ld*(1.f - pd);
    coef[bn*3+2] = a1*ld*pd;
}

// ---------------- Kernel 3: conv_w fp32 -> bf16 ----------------
__global__ __launch_bounds__(256) void k_wconv(const float* __restrict__ w,
                                               ushort* __restrict__ wb) {
    int i = blockIdx.x*blockDim.x + threadIdx.x;
    size_t idx = (size_t)i*4;
    if (idx >= (size_t)NC*NC) return;
    float4 a = *(const float4*)(w + idx);
    ushort4 o;
    o.x = f2bf(a.x); o.y = f2bf(a.y); o.z = f2bf(a.z); o.w = f2bf(a.w);
    *(ushort4*)(wb + idx) = o;
}

// ---------------- Kernel 4: featT — single pass over n (x read ~1.2x) ----------------
__global__ __launch_bounds__(256) void k_feat(const float* __restrict__ x,
                                              const float* __restrict__ coef,
                                              ushort* __restrict__ featT) {
    __shared__ float tile[32*129];
    int hwt = blockIdx.x;         // 0..71
    int b   = blockIdx.y;         // 0..15
    int t = threadIdx.x;
    int hw0 = hwt*32;
    const float* xb = x + (size_t)b*NN*DD;

    int c_[4], ch_[4];
    size_t off_[4];
    #pragma unroll
    for (int i = 0; i < 4; ++i) {
        int s = i*256 + t;
        c_[i] = s >> 3; ch_[i] = s & 7;
        off_[i] = (size_t)c_[i]*HWD + hw0 + ch_[i]*4;
    }

    float4 s0[4], s1[4], s2[4], s3[4];
    #pragma unroll
    for (int i = 0; i < 4; ++i) s0[i] = *(const float4*)(xb + (size_t)0*DD + off_[i]);
    #pragma unroll
    for (int i = 0; i < 4; ++i) s1[i] = *(const float4*)(xb + (size_t)1*DD + off_[i]);
    #pragma unroll
    for (int i = 0; i < 4; ++i) s2[i] = *(const float4*)(xb + (size_t)2*DD + off_[i]);

    for (int n = 0; n < NN; ++n) {
        int n3 = (n + 3) % NN;
        #pragma unroll
        for (int i = 0; i < 4; ++i) s3[i] = *(const float4*)(xb + (size_t)n3*DD + off_[i]);

        int bn = b*NN + n;
        float c0 = coef[bn*3+0], c1 = coef[bn*3+1], c2 = coef[bn*3+2];

        #pragma unroll
        for (int i = 0; i < 4; ++i) {
            int hwb = ch_[i]*4, cc = c_[i];
            tile[(hwb+0)*129 + cc] = c0*s0[i].x + c1*s1[i].x + c2*s2[i].x;
            tile[(hwb+1)*129 + cc] = c0*s0[i].y + c1*s1[i].y + c2*s2[i].y;
            tile[(hwb+2)*129 + cc] = c0*s0[i].z + c1*s1[i].z + c2*s2[i].z;
            tile[(hwb+3)*129 + cc] = c0*s0[i].w + c1*s1[i].w + c2*s2[i].w;
        }
        __syncthreads();

        int hwl = t >> 4;             // 0..15
        int cc0 = (t & 15) * 8;       // 0..120
        #pragma unroll
        for (int p = 0; p < 2; ++p) {
            int hw = p*16 + hwl;
            const float* src = &tile[hw*129 + cc0];
            union { ushort us[8]; uint4 v; } pk;
            #pragma unroll
            for (int j = 0; j < 8; ++j) pk.us[j] = f2bf(src[j]);
            ushort* dst = featT + (size_t)b*HWD*NC + (size_t)(hw0 + hw)*NC + n*CC + cc0;
            *(uint4*)dst = pk.v;
        }
        __syncthreads();
        #pragma unroll
        for (int i = 0; i < 4; ++i) { s0[i] = s1[i]; s1[i] = s2[i]; s2[i] = s3[i]; }
    }
}

// ---------------- Kernel 5: LDS-FREE 128x128x32 GEMM — frags direct from L2/L3 ----------------
// No LDS, no global_load_lds, no barriers. Each wave streams its MFMA fragments
// straight from W (L2-hot, 3.3 MB/XCD) and featT (L2/L3) into registers,
// double-buffered over 2 K-steps (hand-unrolled for static reg indexing).
// A-frag pattern: 16 rows x 64B contiguous per instr (full-width L2 transactions).
// Waves free-run -> MFMA/VMEM overlap across ~12 waves/CU (m114 mechanism).
__global__ __launch_bounds__(256, 3) void k_gemm(const ushort* __restrict__ Wb,
                                                 const ushort* __restrict__ featT,
                                                 const float* __restrict__ bias,
                                                 const float* __restrict__ x,
                                                 float* __restrict__ out) {
    // XCD-chunked mapping, o fastest: per XCD, W hot in L2; featT panels
    // get 10-consecutive-block reuse.
    int bid = blockIdx.x;
    int wkid = (bid & 7) * 360 + (bid >> 3);   // 2880 = 8*360, bijective
    int b    = wkid / 180;
    int rem  = wkid % 180;
    int hwt  = rem / 10;
    int ot   = rem % 10;
    int o0 = ot*BM, hw0 = hwt*BN;

    int t = threadIdx.x;
    int l = t & 63;
    int w = t >> 6;
    int wr = w >> 1, wc = w & 1;      // 2x2 wave grid, 64x64 per wave

    int fr = l & 15;
    int kc = (l >> 4) * 8;            // 0,8,16,24 (ushort offset within K-step)

    // per-lane fragment base pointers (advance by 32 ushorts per K-step)
    const ushort* Abase = Wb    + (size_t)(o0 + wr*64 + fr)*NC + kc;
    const ushort* Bbase = featT + (size_t)b*HWD*NC + (size_t)(hw0 + wc*64 + fr)*NC + kc;

    f32x4 acc[4][4] = {};
    bf16x8 a0[4], b0[4], a1[4], b1[4];

#define LOADF(af_, bf_, kt_) do { \
    size_t ko_ = (size_t)(kt_)*BK; \
    _Pragma("unroll") \
    for (int m = 0; m < 4; ++m) af_[m] = *(const bf16x8*)(Abase + (size_t)m*16*NC + ko_); \
    _Pragma("unroll") \
    for (int n = 0; n < 4; ++n) bf_[n] = *(const bf16x8*)(Bbase + (size_t)n*16*NC + ko_); \
} while (0)

#define MFMA16(af_, bf_) do { \
    _Pragma("unroll") \
    for (int m = 0; m < 4; ++m) \
        _Pragma("unroll") \
        for (int n = 0; n < 4; ++n) \
            acc[m][n] = __builtin_amdgcn_mfma_f32_16x16x32_bf16(af_[m], bf_[n], acc[m][n], 0, 0, 0); \
} while (0)

    LOADF(a0, b0, 0);
    for (int kt = 0; kt + 2 < TK; kt += 2) {
        LOADF(a1, b1, kt + 1);
        MFMA16(a0, b0);
        LOADF(a0, b0, kt + 2);
        MFMA16(a1, b1);
    }
    // TK = 40 (even): loop exits having computed 0..37, a0 holds kt=38
    LOADF(a1, b1, TK - 1);
    MFMA16(a0, b0);
    MFMA16(a1, b1);

#undef LOADF
#undef MFMA16

    // epilogue: + bias + residual x
    #pragma unroll
    for (int m = 0; m < 4; ++m) {
        int ro_base = o0 + wr*64 + m*16 + ((l >> 4) << 2);
        #pragma unroll
        for (int n = 0; n < 4; ++n) {
            int col = hw0 + wc*64 + n*16 + (l & 15);
            #pragma unroll
            for (int r = 0; r < 4; ++r) {
                int ro = ro_base + r;
                size_t idx = (size_t)b*NC*HWD + (size_t)ro*HWD + col;
                out[idx] = acc[m][n][r] + bias[ro] + x[idx];
            }
        }
    }
}

extern "C" void kernel_launch(void* const* d_in, const int* in_sizes, int n_in,
                              void* d_out, int out_size, void* d_ws, size_t ws_size,
                              hipStream_t stream) {
    const float* x       = (const float*)d_in[0];
    const float* pos_dec = (const float*)d_in[1];
    const float* len_dec = (const float*)d_in[2];
    const float* conv_w  = (const float*)d_in[3];
    const float* conv_b  = (const float*)d_in[4];
    float* out = (float*)d_out;

    char* ws = (char*)d_ws;
    ushort* featT = (ushort*)ws;                                   // 94,371,840 B
    ushort* wb    = (ushort*)(ws + FEAT_BYTES);                    // 3,276,800 B
    float*  part  = (float*)(ws + FEAT_BYTES + WB_BYTES);          // 138,240 B
    float*  coef  = part + PART_FLOATS;                            // 1,920 B

    k_dots <<<dim3(BB*CH2), 256, 0, stream>>>(x, part);
    k_coef <<<dim3(1), 256, 0, stream>>>(part, pos_dec, len_dec, coef);
    k_wconv<<<dim3(1600), 256, 0, stream>>>(conv_w, wb);
    k_feat <<<dim3(72, BB), 256, 0, stream>>>(x, coef, featT);
    k_gemm <<<dim3(2880), 256, 0, stream>>>(wb, featT, conv_b, x, out);
}

// Round 12
// 285.345 us; speedup vs baseline: 2.0932x; 2.0932x over previous
//
#include <hip/hip_runtime.h>
#include <hip/hip_bf16.h>

#define BB 16
#define NN 10
#define CC 128
#define HWD 2304            // 48*48
#define DD (CC*HWD)         // 294912
#define NC (NN*CC)          // 1280

#define CHP 72              // hw-chunks per (b,n) for dot partials

#define BM 256
#define BN 256
#define BK 64
#define TK (NC/BK)          // 20 K-tiles

typedef __bf16 bf16x8 __attribute__((ext_vector_type(8)));
typedef float  f32x4  __attribute__((ext_vector_type(4)));

#define XT_BYTES ((size_t)BB*HWD*NC*2)       // 94,371,840
#define W2_BYTES ((size_t)BB*NC*NC*2)        // 52,428,800
#define WB_BYTES ((size_t)NC*NC*2)           // 3,276,800
#define PART_FLOATS (BB*NN*CHP*3)            // 34,560
#define HEAD ((size_t)262144)                // part + coef region

__device__ __forceinline__ ushort f2bf(float f) {
    __hip_bfloat16 h = __float2bfloat16(f);
    return *reinterpret_cast<ushort*>(&h);
}

__device__ __forceinline__ void gload_lds16(const ushort* g, ushort* l) {
    __builtin_amdgcn_global_load_lds(
        (const __attribute__((address_space(1))) void*)(const void*)g,
        (__attribute__((address_space(3))) void*)(void*)l,
        16, 0, 0);
}

// ---------------- Kernel 1: fused transpose+cast+dots — single pass over x ----------------
// Block (hwt, b): walks n=0..9 holding slices n,n+1,n+2 in registers (prefetch n+3).
// Per n: (a) accumulate d0,d1,d2 partials (fp32, from fp32 source), (b) write
// xT[b][hw][n*128+c] = bf16(x[b][n*128+c][hw]) via LDS transpose.
__global__ __launch_bounds__(256) void k_trans(const float* __restrict__ x,
                                               ushort* __restrict__ xT,
                                               float* __restrict__ part) {
    __shared__ float tile[32*129];
    __shared__ float red[4][3];
    int hwt = blockIdx.x;         // 0..71
    int b   = blockIdx.y;         // 0..15
    int t = threadIdx.x;
    int hw0 = hwt*32;
    const float* xb = x + (size_t)b*NN*DD;

    int c_[4], ch_[4];
    size_t off_[4];
    #pragma unroll
    for (int i = 0; i < 4; ++i) {
        int s = i*256 + t;
        c_[i] = s >> 3; ch_[i] = s & 7;
        off_[i] = (size_t)c_[i]*HWD + hw0 + ch_[i]*4;
    }

    float4 s0[4], s1[4], s2[4], s3[4];
    #pragma unroll
    for (int i = 0; i < 4; ++i) s0[i] = *(const float4*)(xb + (size_t)0*DD + off_[i]);
    #pragma unroll
    for (int i = 0; i < 4; ++i) s1[i] = *(const float4*)(xb + (size_t)1*DD + off_[i]);
    #pragma unroll
    for (int i = 0; i < 4; ++i) s2[i] = *(const float4*)(xb + (size_t)2*DD + off_[i]);

    int w = t >> 6, l = t & 63;

    for (int n = 0; n < NN; ++n) {
        int n3 = (n + 3) % NN;
        #pragma unroll
        for (int i = 0; i < 4; ++i) s3[i] = *(const float4*)(xb + (size_t)n3*DD + off_[i]);

        // dots
        float d0 = 0.f, d1 = 0.f, d2 = 0.f;
        #pragma unroll
        for (int i = 0; i < 4; ++i) {
            d0 += s0[i].x*s0[i].x + s0[i].y*s0[i].y + s0[i].z*s0[i].z + s0[i].w*s0[i].w;
            d1 += s0[i].x*s1[i].x + s0[i].y*s1[i].y + s0[i].z*s1[i].z + s0[i].w*s1[i].w;
            d2 += s0[i].x*s2[i].x + s0[i].y*s2[i].y + s0[i].z*s2[i].z + s0[i].w*s2[i].w;
        }
        for (int o = 32; o > 0; o >>= 1) {
            d0 += __shfl_down(d0, o);
            d1 += __shfl_down(d1, o);
            d2 += __shfl_down(d2, o);
        }
        if (l == 0) { red[w][0] = d0; red[w][1] = d1; red[w][2] = d2; }

        // transpose fill (s0 = x[n])
        #pragma unroll
        for (int i = 0; i < 4; ++i) {
            int hwb = ch_[i]*4, cc = c_[i];
            tile[(hwb+0)*129 + cc] = s0[i].x;
            tile[(hwb+1)*129 + cc] = s0[i].y;
            tile[(hwb+2)*129 + cc] = s0[i].z;
            tile[(hwb+3)*129 + cc] = s0[i].w;
        }
        __syncthreads();

        if (t == 0) {
            float r0 = 0.f, r1 = 0.f, r2 = 0.f;
            #pragma unroll
            for (int i = 0; i < 4; ++i) { r0 += red[i][0]; r1 += red[i][1]; r2 += red[i][2]; }
            float* o = part + ((size_t)(b*NN + n)*CHP + hwt)*3;
            o[0] = r0; o[1] = r1; o[2] = r2;
        }

        int hwl = t >> 4;             // 0..15
        int cc0 = (t & 15) * 8;       // 0..120
        #pragma unroll
        for (int p = 0; p < 2; ++p) {
            int hw = p*16 + hwl;
            const float* src = &tile[hw*129 + cc0];
            union { ushort us[8]; uint4 v; } pk;
            #pragma unroll
            for (int j = 0; j < 8; ++j) pk.us[j] = f2bf(src[j]);
            ushort* dst = xT + (size_t)b*HWD*NC + (size_t)(hw0 + hw)*NC + n*CC + cc0;
            *(uint4*)dst = pk.v;
        }
        __syncthreads();
        #pragma unroll
        for (int i = 0; i < 4; ++i) { s0[i] = s1[i]; s1[i] = s2[i]; s2[i] = s3[i]; }
    }
}

// ---------------- Kernel 2: softmax -> combination coefficients ----------------
__global__ void k_coef(const float* __restrict__ part,
                       const float* __restrict__ pos_dec,
                       const float* __restrict__ len_dec,
                       float* __restrict__ coef) {
    int bn = threadIdx.x;
    if (bn >= BB*NN) return;
    int n = bn % NN;
    float d0 = 0.f, d1 = 0.f, d2 = 0.f;
    const float* p = part + (size_t)bn*CHP*3;
    for (int i = 0; i < CHP; ++i) { d0 += p[i*3]; d1 += p[i*3+1]; d2 += p[i*3+2]; }
    float pd = pos_dec[n], ld = len_dec[n];
    float l0 = (1.f - pd)*d0 + pd*d1;
    float l1 = ld*((1.f - pd)*d1 + pd*d2);
    float m  = fmaxf(l0, l1);
    float e0 = expf(l0 - m), e1 = expf(l1 - m);
    float inv = 1.f/(e0 + e1);
    float a0 = e0*inv, a1 = e1*inv;
    coef[bn*3+0] = a0*(1.f - pd);
    coef[bn*3+1] = a0*pd + a1*ld*(1.f - pd);
    coef[bn*3+2] = a1*ld*pd;
}

// ---------------- Kernel 3a: W2[b][o][mc] = folded per-batch weights (bf16) ----------------
// W2[b][o, m*128+c] = c0[b,m]*W[o,m*128+c] + c1[b,m-1]*W[o,(m-1)*128+c]
//                   + c2[b,m-2]*W[o,(m-2)*128+c]
__global__ __launch_bounds__(256) void k_w2(const float* __restrict__ w,
                                            const float* __restrict__ coef,
                                            ushort* __restrict__ w2) {
    int b = blockIdx.y;
    size_t eid = ((size_t)blockIdx.x*256 + threadIdx.x)*8;
    int o  = (int)(eid / NC);
    int mc = (int)(eid % NC);
    int m = mc >> 7, c = mc & 127;
    int m1 = (m + 9) % 10, m2 = (m + 8) % 10;
    float c0 = coef[(b*NN + m )*3 + 0];
    float c1 = coef[(b*NN + m1)*3 + 1];
    float c2 = coef[(b*NN + m2)*3 + 2];
    const float* wr = w + (size_t)o*NC;
    float4 a0 = *(const float4*)(wr + m *128 + c);
    float4 a1 = *(const float4*)(wr + m *128 + c + 4);
    float4 u0 = *(const float4*)(wr + m1*128 + c);
    float4 u1 = *(const float4*)(wr + m1*128 + c + 4);
    float4 v0 = *(const float4*)(wr + m2*128 + c);
    float4 v1 = *(const float4*)(wr + m2*128 + c + 4);
    union { ushort us[8]; uint4 v; } pk;
    pk.us[0] = f2bf(c0*a0.x + c1*u0.x + c2*v0.x);
    pk.us[1] = f2bf(c0*a0.y + c1*u0.y + c2*v0.y);
    pk.us[2] = f2bf(c0*a0.z + c1*u0.z + c2*v0.z);
    pk.us[3] = f2bf(c0*a0.w + c1*u0.w + c2*v0.w);
    pk.us[4] = f2bf(c0*a1.x + c1*u1.x + c2*v1.x);
    pk.us[5] = f2bf(c0*a1.y + c1*u1.y + c2*v1.y);
    pk.us[6] = f2bf(c0*a1.z + c1*u1.z + c2*v1.z);
    pk.us[7] = f2bf(c0*a1.w + c1*u1.w + c2*v1.w);
    *(uint4*)(w2 + (size_t)b*NC*NC + eid) = pk.v;
}

// ---------------- Kernel 3b (fallback): conv_w fp32 -> bf16 ----------------
__global__ __launch_bounds__(256) void k_wconv(const float* __restrict__ w,
                                               ushort* __restrict__ wb) {
    int i = blockIdx.x*blockDim.x + threadIdx.x;
    size_t idx = (size_t)i*4;
    if (idx >= (size_t)NC*NC) return;
    float4 a = *(const float4*)(w + idx);
    ushort4 o;
    o.x = f2bf(a.x); o.y = f2bf(a.y); o.z = f2bf(a.z); o.w = f2bf(a.w);
    *(ushort4*)(wb + idx) = o;
}

// ---------------- Kernel 4 (fallback): featT combo (coef-dependent) ----------------
__global__ __launch_bounds__(256) void k_feat(const float* __restrict__ x,
                                              const float* __restrict__ coef,
                                              ushort* __restrict__ featT) {
    __shared__ float tile[32*129];
    int hwt = blockIdx.x;
    int b   = blockIdx.y;
    int t = threadIdx.x;
    int hw0 = hwt*32;
    const float* xb = x + (size_t)b*NN*DD;

    int c_[4], ch_[4];
    size_t off_[4];
    #pragma unroll
    for (int i = 0; i < 4; ++i) {
        int s = i*256 + t;
        c_[i] = s >> 3; ch_[i] = s & 7;
        off_[i] = (size_t)c_[i]*HWD + hw0 + ch_[i]*4;
    }

    float4 s0[4], s1[4], s2[4], s3[4];
    #pragma unroll
    for (int i = 0; i < 4; ++i) s0[i] = *(const float4*)(xb + (size_t)0*DD + off_[i]);
    #pragma unroll
    for (int i = 0; i < 4; ++i) s1[i] = *(const float4*)(xb + (size_t)1*DD + off_[i]);
    #pragma unroll
    for (int i = 0; i < 4; ++i) s2[i] = *(const float4*)(xb + (size_t)2*DD + off_[i]);

    for (int n = 0; n < NN; ++n) {
        int n3 = (n + 3) % NN;
        #pragma unroll
        for (int i = 0; i < 4; ++i) s3[i] = *(const float4*)(xb + (size_t)n3*DD + off_[i]);

        int bn = b*NN + n;
        float c0 = coef[bn*3+0], c1 = coef[bn*3+1], c2 = coef[bn*3+2];

        #pragma unroll
        for (int i = 0; i < 4; ++i) {
            int hwb = ch_[i]*4, cc = c_[i];
            tile[(hwb+0)*129 + cc] = c0*s0[i].x + c1*s1[i].x + c2*s2[i].x;
            tile[(hwb+1)*129 + cc] = c0*s0[i].y + c1*s1[i].y + c2*s2[i].y;
            tile[(hwb+2)*129 + cc] = c0*s0[i].z + c1*s1[i].z + c2*s2[i].z;
            tile[(hwb+3)*129 + cc] = c0*s0[i].w + c1*s1[i].w + c2*s2[i].w;
        }
        __syncthreads();

        int hwl = t >> 4;
        int cc0 = (t & 15) * 8;
        #pragma unroll
        for (int p = 0; p < 2; ++p) {
            int hw = p*16 + hwl;
            const float* src = &tile[hw*129 + cc0];
            union { ushort us[8]; uint4 v; } pk;
            #pragma unroll
            for (int j = 0; j < 8; ++j) pk.us[j] = f2bf(src[j]);
            ushort* dst = featT + (size_t)b*HWD*NC + (size_t)(hw0 + hw)*NC + n*CC + cc0;
            *(uint4*)dst = pk.v;
        }
        __syncthreads();
        #pragma unroll
        for (int i = 0; i < 4; ++i) { s0[i] = s1[i]; s1[i] = s2[i]; s2[i] = s3[i]; }
    }
}

// ---------------- Kernel 5: 256x256x64, 4-phase/K-tile, branch-free counted vmcnt ----------------
// R10 structure (best measured). A has per-batch stride aStride (W2) or 0 (shared W).
#define BAR()   __builtin_amdgcn_s_barrier()
#define SB()    __builtin_amdgcn_sched_barrier(0)
#define LGKM0() asm volatile("s_waitcnt lgkmcnt(0)" ::: "memory")
#define VM(N)   asm volatile("s_waitcnt vmcnt(" #N ")" ::: "memory")

__global__ __launch_bounds__(512, 2) void k_gemm(const ushort* __restrict__ Amat,
                                                 const ushort* __restrict__ Bmat,
                                                 const float* __restrict__ bias,
                                                 const float* __restrict__ x,
                                                 float* __restrict__ out,
                                                 size_t aStride) {
    __shared__ ushort L[2][4][BM*32];   // 2 bufs x 4 regions x 16 KiB = 128 KiB

    int bid = blockIdx.x;
    int wkid = (bid & 7) * 90 + (bid >> 3);   // bijective XCD swizzle (720 = 8*90)
    int b   = wkid / 45;                      // 2 b's per XCD -> W2[b] L2-resident
    int r45 = wkid % 45;
    int hwt = r45 / 5;
    int ot  = r45 % 5;
    int o0 = ot*BM, hw0 = hwt*BN;

    int t = threadIdx.x;
    int l = t & 63;
    int w = t >> 6;
    int wr = w >> 2, wc = w & 3;      // 2(M) x 4(N) waves; wave tile 128x64

    const ushort* Ag = Amat + (size_t)b*aStride + (size_t)o0*NC;
    const ushort* Bg = Bmat + (size_t)b*HWD*NC + (size_t)hw0*NC;

    int r0 = t >> 2, c0 = t & 3;
    size_t g0 = (size_t)r0*NC + (size_t)((c0 ^ ((r0 >> 1) & 3)) * 8);
    size_t g1 = g0 + (size_t)128*NC;

#define STAGE(nb_, reg_, gp_) do { \
    gload_lds16((gp_) + g0, &L[nb_][reg_][t*8]); \
    gload_lds16((gp_) + g1, &L[nb_][reg_][(512 + t)*8]); } while (0)

    int fr = l & 15;
    int kc = ((l >> 4) ^ ((l >> 1) & 3)) * 8;
    int rowA = (wr*128 + fr)*32 + kc;     // + i*512
    int rowB = (wc*64  + fr)*32 + kc;     // + n*512

    f32x4 acc[8][4] = {};
    bf16x8 af[8], bfA, bfB;

    STAGE(0, 0, Ag);                 // Aklo(0)
    STAGE(0, 2, Bg);                 // Bklo(0)
    STAGE(0, 1, Ag + 32);            // Akhi(0)
    STAGE(0, 3, Bg + 32);            // Bkhi(0)
    VM(4);
    BAR(); SB();

    for (int kt = 0; kt < TK - 1; ++kt) {
        int buf = kt & 1, nbuf = buf ^ 1;
        const ushort* A0 = &L[buf][0][0];
        const ushort* A1 = &L[buf][1][0];
        const ushort* B0 = &L[buf][2][0];
        const ushort* B1 = &L[buf][3][0];
        const ushort* Agk = Ag + (size_t)(kt + 1)*BK;
        const ushort* Bgk = Bg + (size_t)(kt + 1)*BK;

        // ---- ph1: klo, n01 ----
        #pragma unroll
        for (int i = 0; i < 8; ++i) af[i] = *(const bf16x8*)&A0[rowA + i*512];
        bfA = *(const bf16x8*)&B0[rowB];
        bfB = *(const bf16x8*)&B0[rowB + 512];
        STAGE(nbuf, 0, Agk);
        SB(); BAR(); LGKM0(); SB();
        __builtin_amdgcn_s_setprio(1);
        #pragma unroll
        for (int i = 0; i < 8; ++i) {
            acc[i][0] = __builtin_amdgcn_mfma_f32_16x16x32_bf16(af[i], bfA, acc[i][0], 0, 0, 0);
            acc[i][1] = __builtin_amdgcn_mfma_f32_16x16x32_bf16(af[i], bfB, acc[i][1], 0, 0, 0);
        }
        __builtin_amdgcn_s_setprio(0);
        SB(); BAR(); SB();

        // ---- ph2: klo, n23 ----
        bfA = *(const bf16x8*)&B0[rowB + 2*512];
        bfB = *(const bf16x8*)&B0[rowB + 3*512];
        STAGE(nbuf, 2, Bgk);
        SB(); BAR(); LGKM0(); SB();
        __builtin_amdgcn_s_setprio(1);
        #pragma unroll
        for (int i = 0; i < 8; ++i) {
            acc[i][2] = __builtin_amdgcn_mfma_f32_16x16x32_bf16(af[i], bfA, acc[i][2], 0, 0, 0);
            acc[i][3] = __builtin_amdgcn_mfma_f32_16x16x32_bf16(af[i], bfB, acc[i][3], 0, 0, 0);
        }
        __builtin_amdgcn_s_setprio(0);
        SB(); VM(4); BAR(); SB();

        // ---- ph3: khi, n01 ----
        #pragma unroll
        for (int i = 0; i < 8; ++i) af[i] = *(const bf16x8*)&A1[rowA + i*512];
        bfA = *(const bf16x8*)&B1[rowB];
        bfB = *(const bf16x8*)&B1[rowB + 512];
        STAGE(nbuf, 1, Agk + 32);
        SB(); BAR(); LGKM0(); SB();
        __builtin_amdgcn_s_setprio(1);
        #pragma unroll
        for (int i = 0; i < 8; ++i) {
            acc[i][0] = __builtin_amdgcn_mfma_f32_16x16x32_bf16(af[i], bfA, acc[i][0], 0, 0, 0);
            acc[i][1] = __builtin_amdgcn_mfma_f32_16x16x32_bf16(af[i], bfB, acc[i][1], 0, 0, 0);
        }
        __builtin_amdgcn_s_setprio(0);
        SB(); BAR(); SB();

        // ---- ph4: khi, n23 ----
        bfA = *(const bf16x8*)&B1[rowB + 2*512];
        bfB = *(const bf16x8*)&B1[rowB + 3*512];
        STAGE(nbuf, 3, Bgk + 32);
        SB(); BAR(); LGKM0(); SB();
        __builtin_amdgcn_s_setprio(1);
        #pragma unroll
        for (int i = 0; i < 8; ++i) {
            acc[i][2] = __builtin_amdgcn_mfma_f32_16x16x32_bf16(af[i], bfA, acc[i][2], 0, 0, 0);
            acc[i][3] = __builtin_amdgcn_mfma_f32_16x16x32_bf16(af[i], bfB, acc[i][3], 0, 0, 0);
        }
        __builtin_amdgcn_s_setprio(0);
        SB(); VM(4); BAR(); SB();
    }

    // ---- last tile, peeled ----
    {
        const int buf = (TK - 1) & 1;
        const ushort* A0 = &L[buf][0][0];
        const ushort* A1 = &L[buf][1][0];
        const ushort* B0 = &L[buf][2][0];
        const ushort* B1 = &L[buf][3][0];

        #pragma unroll
        for (int i = 0; i < 8; ++i) af[i] = *(const bf16x8*)&A0[rowA + i*512];
        bfA = *(const bf16x8*)&B0[rowB];
        bfB = *(const bf16x8*)&B0[rowB + 512];
        #pragma unroll
        for (int i = 0; i < 8; ++i) {
            acc[i][0] = __builtin_amdgcn_mfma_f32_16x16x32_bf16(af[i], bfA, acc[i][0], 0, 0, 0);
            acc[i][1] = __builtin_amdgcn_mfma_f32_16x16x32_bf16(af[i], bfB, acc[i][1], 0, 0, 0);
        }
        bfA = *(const bf16x8*)&B0[rowB + 2*512];
        bfB = *(const bf16x8*)&B0[rowB + 3*512];
        #pragma unroll
        for (int i = 0; i < 8; ++i) {
            acc[i][2] = __builtin_amdgcn_mfma_f32_16x16x32_bf16(af[i], bfA, acc[i][2], 0, 0, 0);
            acc[i][3] = __builtin_amdgcn_mfma_f32_16x16x32_bf16(af[i], bfB, acc[i][3], 0, 0, 0);
        }
        VM(0);
        BAR(); SB();
        #pragma unroll
        for (int i = 0; i < 8; ++i) af[i] = *(const bf16x8*)&A1[rowA + i*512];
        bfA = *(const bf16x8*)&B1[rowB];
        bfB = *(const bf16x8*)&B1[rowB + 512];
        #pragma unroll
        for (int i = 0; i < 8; ++i) {
            acc[i][0] = __builtin_amdgcn_mfma_f32_16x16x32_bf16(af[i], bfA, acc[i][0], 0, 0, 0);
            acc[i][1] = __builtin_amdgcn_mfma_f32_16x16x32_bf16(af[i], bfB, acc[i][1], 0, 0, 0);
        }
        bfA = *(const bf16x8*)&B1[rowB + 2*512];
        bfB = *(const bf16x8*)&B1[rowB + 3*512];
        #pragma unroll
        for (int i = 0; i < 8; ++i) {
            acc[i][2] = __builtin_amdgcn_mfma_f32_16x16x32_bf16(af[i], bfA, acc[i][2], 0, 0, 0);
            acc[i][3] = __builtin_amdgcn_mfma_f32_16x16x32_bf16(af[i], bfB, acc[i][3], 0, 0, 0);
        }
    }
#undef STAGE

    // epilogue: + bias + residual x
    #pragma unroll
    for (int m = 0; m < 8; ++m) {
        int ro_base = o0 + wr*128 + m*16 + ((l >> 4) << 2);
        #pragma unroll
        for (int n = 0; n < 4; ++n) {
            int col = hw0 + wc*64 + n*16 + (l & 15);
            #pragma unroll
            for (int r = 0; r < 4; ++r) {
                int ro = ro_base + r;
                size_t idx = (size_t)b*NC*HWD + (size_t)ro*HWD + col;
                out[idx] = acc[m][n][r] + bias[ro] + x[idx];
            }
        }
    }
}

extern "C" void kernel_launch(void* const* d_in, const int* in_sizes, int n_in,
                              void* d_out, int out_size, void* d_ws, size_t ws_size,
                              hipStream_t stream) {
    const float* x       = (const float*)d_in[0];
    const float* pos_dec = (const float*)d_in[1];
    const float* len_dec = (const float*)d_in[2];
    const float* conv_w  = (const float*)d_in[3];
    const float* conv_b  = (const float*)d_in[4];
    float* out = (float*)d_out;

    char* ws = (char*)d_ws;
    float*  part = (float*)ws;                    // 138,240 B
    float*  coef = part + PART_FLOATS;            // 1,920 B
    ushort* xT   = (ushort*)(ws + HEAD);          // 94,371,840 B (xT or featT)

    k_trans<<<dim3(CHP, BB), 256, 0, stream>>>(x, xT, part);
    k_coef <<<dim3(1), 256, 0, stream>>>(part, pos_dec, len_dec, coef);

    if (ws_size >= HEAD + XT_BYTES + W2_BYTES) {
        // W2-folded path: coef-independent transpose already done; GEMM on W2[b] @ xT
        ushort* w2 = (ushort*)(ws + HEAD + XT_BYTES);   // 52,428,800 B
        k_w2  <<<dim3(800, BB), 256, 0, stream>>>(conv_w, coef, w2);
        k_gemm<<<dim3(720), 512, 0, stream>>>(w2, xT, conv_b, x, out, (size_t)NC*NC);
    } else {
        // fallback: featT combo pipeline (overwrites xT region with featT)
        ushort* wb = (ushort*)(ws + HEAD + XT_BYTES);   // 3,276,800 B
        k_wconv<<<dim3(1600), 256, 0, stream>>>(conv_w, wb);
        k_feat <<<dim3(CHP, BB), 256, 0, stream>>>(x, coef, xT);
        k_gemm <<<dim3(720), 512, 0, stream>>>(wb, xT, conv_b, x, out, (size_t)0);
    }
}

// Round 13
// 272.355 us; speedup vs baseline: 2.1930x; 1.0477x over previous
//
#include <hip/hip_runtime.h>
#include <hip/hip_bf16.h>

#define BB 16
#define NN 10
#define CC 128
#define HWD 2304            // 48*48
#define DD (CC*HWD)         // 294912
#define NC (NN*CC)          // 1280

#define CHP 72              // hw-chunks per (b,n) for dot partials

#define BM 256
#define BN 256
#define BK 64
#define TK (NC/BK)          // 20 K-tiles

typedef __bf16 bf16x8 __attribute__((ext_vector_type(8)));
typedef float  f32x4  __attribute__((ext_vector_type(4)));
typedef float  f32x16 __attribute__((ext_vector_type(16)));

#define XT_BYTES ((size_t)BB*HWD*NC*2)       // 94,371,840
#define W2_BYTES ((size_t)BB*NC*NC*2)        // 52,428,800
#define WB_BYTES ((size_t)NC*NC*2)           // 3,276,800
#define PART_FLOATS (BB*NN*CHP*3)            // 34,560
#define HEAD ((size_t)262144)                // part + coef region

__device__ __forceinline__ ushort f2bf(float f) {
    __hip_bfloat16 h = __float2bfloat16(f);
    return *reinterpret_cast<ushort*>(&h);
}

__device__ __forceinline__ void gload_lds16(const ushort* g, ushort* l) {
    __builtin_amdgcn_global_load_lds(
        (const __attribute__((address_space(1))) void*)(const void*)g,
        (__attribute__((address_space(3))) void*)(void*)l,
        16, 0, 0);
}

// ---------------- Kernel 1: fused transpose+cast+dots — single pass over x ----------------
__global__ __launch_bounds__(256) void k_trans(const float* __restrict__ x,
                                               ushort* __restrict__ xT,
                                               float* __restrict__ part) {
    __shared__ float tile[32*129];
    __shared__ float red[4][3];
    int hwt = blockIdx.x;         // 0..71
    int b   = blockIdx.y;         // 0..15
    int t = threadIdx.x;
    int hw0 = hwt*32;
    const float* xb = x + (size_t)b*NN*DD;

    int c_[4], ch_[4];
    size_t off_[4];
    #pragma unroll
    for (int i = 0; i < 4; ++i) {
        int s = i*256 + t;
        c_[i] = s >> 3; ch_[i] = s & 7;
        off_[i] = (size_t)c_[i]*HWD + hw0 + ch_[i]*4;
    }

    float4 s0[4], s1[4], s2[4], s3[4];
    #pragma unroll
    for (int i = 0; i < 4; ++i) s0[i] = *(const float4*)(xb + (size_t)0*DD + off_[i]);
    #pragma unroll
    for (int i = 0; i < 4; ++i) s1[i] = *(const float4*)(xb + (size_t)1*DD + off_[i]);
    #pragma unroll
    for (int i = 0; i < 4; ++i) s2[i] = *(const float4*)(xb + (size_t)2*DD + off_[i]);

    int w = t >> 6, l = t & 63;

    for (int n = 0; n < NN; ++n) {
        int n3 = (n + 3) % NN;
        #pragma unroll
        for (int i = 0; i < 4; ++i) s3[i] = *(const float4*)(xb + (size_t)n3*DD + off_[i]);

        float d0 = 0.f, d1 = 0.f, d2 = 0.f;
        #pragma unroll
        for (int i = 0; i < 4; ++i) {
            d0 += s0[i].x*s0[i].x + s0[i].y*s0[i].y + s0[i].z*s0[i].z + s0[i].w*s0[i].w;
            d1 += s0[i].x*s1[i].x + s0[i].y*s1[i].y + s0[i].z*s1[i].z + s0[i].w*s1[i].w;
            d2 += s0[i].x*s2[i].x + s0[i].y*s2[i].y + s0[i].z*s2[i].z + s0[i].w*s2[i].w;
        }
        for (int o = 32; o > 0; o >>= 1) {
            d0 += __shfl_down(d0, o);
            d1 += __shfl_down(d1, o);
            d2 += __shfl_down(d2, o);
        }
        if (l == 0) { red[w][0] = d0; red[w][1] = d1; red[w][2] = d2; }

        #pragma unroll
        for (int i = 0; i < 4; ++i) {
            int hwb = ch_[i]*4, cc = c_[i];
            tile[(hwb+0)*129 + cc] = s0[i].x;
            tile[(hwb+1)*129 + cc] = s0[i].y;
            tile[(hwb+2)*129 + cc] = s0[i].z;
            tile[(hwb+3)*129 + cc] = s0[i].w;
        }
        __syncthreads();

        if (t == 0) {
            float r0 = 0.f, r1 = 0.f, r2 = 0.f;
            #pragma unroll
            for (int i = 0; i < 4; ++i) { r0 += red[i][0]; r1 += red[i][1]; r2 += red[i][2]; }
            float* o = part + ((size_t)(b*NN + n)*CHP + hwt)*3;
            o[0] = r0; o[1] = r1; o[2] = r2;
        }

        int hwl = t >> 4;             // 0..15
        int cc0 = (t & 15) * 8;       // 0..120
        #pragma unroll
        for (int p = 0; p < 2; ++p) {
            int hw = p*16 + hwl;
            const float* src = &tile[hw*129 + cc0];
            union { ushort us[8]; uint4 v; } pk;
            #pragma unroll
            for (int j = 0; j < 8; ++j) pk.us[j] = f2bf(src[j]);
            ushort* dst = xT + (size_t)b*HWD*NC + (size_t)(hw0 + hw)*NC + n*CC + cc0;
            *(uint4*)dst = pk.v;
        }
        __syncthreads();
        #pragma unroll
        for (int i = 0; i < 4; ++i) { s0[i] = s1[i]; s1[i] = s2[i]; s2[i] = s3[i]; }
    }
}

// ---------------- Kernel 2: softmax -> combination coefficients ----------------
__global__ void k_coef(const float* __restrict__ part,
                       const float* __restrict__ pos_dec,
                       const float* __restrict__ len_dec,
                       float* __restrict__ coef) {
    int bn = threadIdx.x;
    if (bn >= BB*NN) return;
    int n = bn % NN;
    float d0 = 0.f, d1 = 0.f, d2 = 0.f;
    const float* p = part + (size_t)bn*CHP*3;
    for (int i = 0; i < CHP; ++i) { d0 += p[i*3]; d1 += p[i*3+1]; d2 += p[i*3+2]; }
    float pd = pos_dec[n], ld = len_dec[n];
    float l0 = (1.f - pd)*d0 + pd*d1;
    float l1 = ld*((1.f - pd)*d1 + pd*d2);
    float m  = fmaxf(l0, l1);
    float e0 = expf(l0 - m), e1 = expf(l1 - m);
    float inv = 1.f/(e0 + e1);
    float a0 = e0*inv, a1 = e1*inv;
    coef[bn*3+0] = a0*(1.f - pd);
    coef[bn*3+1] = a0*pd + a1*ld*(1.f - pd);
    coef[bn*3+2] = a1*ld*pd;
}

// ---------------- Kernel 3a: W2[b][o][mc] = folded per-batch weights (bf16) ----------------
__global__ __launch_bounds__(256) void k_w2(const float* __restrict__ w,
                                            const float* __restrict__ coef,
                                            ushort* __restrict__ w2) {
    int b = blockIdx.y;
    size_t eid = ((size_t)blockIdx.x*256 + threadIdx.x)*8;
    int o  = (int)(eid / NC);
    int mc = (int)(eid % NC);
    int m = mc >> 7, c = mc & 127;
    int m1 = (m + 9) % 10, m2 = (m + 8) % 10;
    float c0 = coef[(b*NN + m )*3 + 0];
    float c1 = coef[(b*NN + m1)*3 + 1];
    float c2 = coef[(b*NN + m2)*3 + 2];
    const float* wr = w + (size_t)o*NC;
    float4 a0 = *(const float4*)(wr + m *128 + c);
    float4 a1 = *(const float4*)(wr + m *128 + c + 4);
    float4 u0 = *(const float4*)(wr + m1*128 + c);
    float4 u1 = *(const float4*)(wr + m1*128 + c + 4);
    float4 v0 = *(const float4*)(wr + m2*128 + c);
    float4 v1 = *(const float4*)(wr + m2*128 + c + 4);
    union { ushort us[8]; uint4 v; } pk;
    pk.us[0] = f2bf(c0*a0.x + c1*u0.x + c2*v0.x);
    pk.us[1] = f2bf(c0*a0.y + c1*u0.y + c2*v0.y);
    pk.us[2] = f2bf(c0*a0.z + c1*u0.z + c2*v0.z);
    pk.us[3] = f2bf(c0*a0.w + c1*u0.w + c2*v0.w);
    pk.us[4] = f2bf(c0*a1.x + c1*u1.x + c2*v1.x);
    pk.us[5] = f2bf(c0*a1.y + c1*u1.y + c2*v1.y);
    pk.us[6] = f2bf(c0*a1.z + c1*u1.z + c2*v1.z);
    pk.us[7] = f2bf(c0*a1.w + c1*u1.w + c2*v1.w);
    *(uint4*)(w2 + (size_t)b*NC*NC + eid) = pk.v;
}

// ---------------- Kernel 3b (fallback): conv_w fp32 -> bf16 ----------------
__global__ __launch_bounds__(256) void k_wconv(const float* __restrict__ w,
                                               ushort* __restrict__ wb) {
    int i = blockIdx.x*blockDim.x + threadIdx.x;
    size_t idx = (size_t)i*4;
    if (idx >= (size_t)NC*NC) return;
    float4 a = *(const float4*)(w + idx);
    ushort4 o;
    o.x = f2bf(a.x); o.y = f2bf(a.y); o.z = f2bf(a.z); o.w = f2bf(a.w);
    *(ushort4*)(wb + idx) = o;
}

// ---------------- Kernel 4 (fallback): featT combo (coef-dependent) ----------------
__global__ __launch_bounds__(256) void k_feat(const float* __restrict__ x,
                                              const float* __restrict__ coef,
                                              ushort* __restrict__ featT) {
    __shared__ float tile[32*129];
    int hwt = blockIdx.x;
    int b   = blockIdx.y;
    int t = threadIdx.x;
    int hw0 = hwt*32;
    const float* xb = x + (size_t)b*NN*DD;

    int c_[4], ch_[4];
    size_t off_[4];
    #pragma unroll
    for (int i = 0; i < 4; ++i) {
        int s = i*256 + t;
        c_[i] = s >> 3; ch_[i] = s & 7;
        off_[i] = (size_t)c_[i]*HWD + hw0 + ch_[i]*4;
    }

    float4 s0[4], s1[4], s2[4], s3[4];
    #pragma unroll
    for (int i = 0; i < 4; ++i) s0[i] = *(const float4*)(xb + (size_t)0*DD + off_[i]);
    #pragma unroll
    for (int i = 0; i < 4; ++i) s1[i] = *(const float4*)(xb + (size_t)1*DD + off_[i]);
    #pragma unroll
    for (int i = 0; i < 4; ++i) s2[i] = *(const float4*)(xb + (size_t)2*DD + off_[i]);

    for (int n = 0; n < NN; ++n) {
        int n3 = (n + 3) % NN;
        #pragma unroll
        for (int i = 0; i < 4; ++i) s3[i] = *(const float4*)(xb + (size_t)n3*DD + off_[i]);

        int bn = b*NN + n;
        float c0 = coef[bn*3+0], c1 = coef[bn*3+1], c2 = coef[bn*3+2];

        #pragma unroll
        for (int i = 0; i < 4; ++i) {
            int hwb = ch_[i]*4, cc = c_[i];
            tile[(hwb+0)*129 + cc] = c0*s0[i].x + c1*s1[i].x + c2*s2[i].x;
            tile[(hwb+1)*129 + cc] = c0*s0[i].y + c1*s1[i].y + c2*s2[i].y;
            tile[(hwb+2)*129 + cc] = c0*s0[i].z + c1*s1[i].z + c2*s2[i].z;
            tile[(hwb+3)*129 + cc] = c0*s0[i].w + c1*s1[i].w + c2*s2[i].w;
        }
        __syncthreads();

        int hwl = t >> 4;
        int cc0 = (t & 15) * 8;
        #pragma unroll
        for (int p = 0; p < 2; ++p) {
            int hw = p*16 + hwl;
            const float* src = &tile[hw*129 + cc0];
            union { ushort us[8]; uint4 v; } pk;
            #pragma unroll
            for (int j = 0; j < 8; ++j) pk.us[j] = f2bf(src[j]);
            ushort* dst = featT + (size_t)b*HWD*NC + (size_t)(hw0 + hw)*NC + n*CC + cc0;
            *(uint4*)dst = pk.v;
        }
        __syncthreads();
        #pragma unroll
        for (int i = 0; i < 4; ++i) { s0[i] = s1[i]; s1[i] = s2[i]; s2[i] = s3[i]; }
    }
}

// ---------------- Kernel 5: 256x256x64, 4-phase, counted vmcnt, 32x32x16 MFMA ----------------
// R10/R12 skeleton unchanged; MFMA shape switched to 32x32x16 (half the MFMA
// instruction count per FLOP). Fragment lane-pattern within each 16-lane group is
// identical to the proven zero-conflict layout. C/D mapping (m74/m101 verified):
// col = lane&31, row = (reg&3) + 8*(reg>>2) + 4*(lane>>5).
#define BAR()   __builtin_amdgcn_s_barrier()
#define SB()    __builtin_amdgcn_sched_barrier(0)
#define LGKM0() asm volatile("s_waitcnt lgkmcnt(0)" ::: "memory")
#define VM(N)   asm volatile("s_waitcnt vmcnt(" #N ")" ::: "memory")

__global__ __launch_bounds__(512, 2) void k_gemm(const ushort* __restrict__ Amat,
                                                 const ushort* __restrict__ Bmat,
                                                 const float* __restrict__ bias,
                                                 const float* __restrict__ x,
                                                 float* __restrict__ out,
                                                 size_t aStride) {
    __shared__ ushort L[2][4][BM*32];   // 2 bufs x 4 regions x 16 KiB = 128 KiB

    int bid = blockIdx.x;
    int wkid = (bid & 7) * 90 + (bid >> 3);   // bijective XCD swizzle (720 = 8*90)
    int b   = wkid / 45;
    int r45 = wkid % 45;
    int hwt = r45 / 5;
    int ot  = r45 % 5;
    int o0 = ot*BM, hw0 = hwt*BN;

    int t = threadIdx.x;
    int l = t & 63;
    int w = t >> 6;
    int wr = w >> 2, wc = w & 3;      // 2(M) x 4(N) waves; wave tile 128x64

    const ushort* Ag = Amat + (size_t)b*aStride + (size_t)o0*NC;
    const ushort* Bg = Bmat + (size_t)b*HWD*NC + (size_t)hw0*NC;

    int r0 = t >> 2, c0 = t & 3;
    size_t g0 = (size_t)r0*NC + (size_t)((c0 ^ ((r0 >> 1) & 3)) * 8);
    size_t g1 = g0 + (size_t)128*NC;

#define STAGE(nb_, reg_, gp_) do { \
    gload_lds16((gp_) + g0, &L[nb_][reg_][t*8]); \
    gload_lds16((gp_) + g1, &L[nb_][reg_][(512 + t)*8]); } while (0)

    // 32x32x16 fragment constants: lane row = l&31, K-half = l>>5
    int fr32 = l & 31;
    int kh   = l >> 5;                       // 0/1
    int sw   = (fr32 >> 1) & 3;              // swizzle bits (region rows are 32-aligned)
    int kcA  = ((kh)     ^ sw) << 3;         // chunk for kq=0 within a 32k region
    int kcB  = ((2 | kh) ^ sw) << 3;         // chunk for kq=1
    int rA   = (wr*128 + fr32)*32;           // + mt*1024
    int rB   = (wc*64  + fr32)*32;           // + nt*1024

    f32x16 acc[4][2] = {};
    bf16x8 af[8], bf0, bf1;

    STAGE(0, 0, Ag);                 // Aklo(0)
    STAGE(0, 2, Bg);                 // Bklo(0)
    STAGE(0, 1, Ag + 32);            // Akhi(0)
    STAGE(0, 3, Bg + 32);            // Bkhi(0)
    VM(4);
    BAR(); SB();

#define MFMA8(accn_) do { \
    _Pragma("unroll") \
    for (int mt = 0; mt < 4; ++mt) { \
        acc[mt][accn_] = __builtin_amdgcn_mfma_f32_32x32x16_bf16(af[mt*2+0], bf0, acc[mt][accn_], 0, 0, 0); \
        acc[mt][accn_] = __builtin_amdgcn_mfma_f32_32x32x16_bf16(af[mt*2+1], bf1, acc[mt][accn_], 0, 0, 0); \
    } } while (0)

    for (int kt = 0; kt < TK - 1; ++kt) {
        int buf = kt & 1, nbuf = buf ^ 1;
        const ushort* A0 = &L[buf][0][0];
        const ushort* A1 = &L[buf][1][0];
        const ushort* B0 = &L[buf][2][0];
        const ushort* B1 = &L[buf][3][0];
        const ushort* Agk = Ag + (size_t)(kt + 1)*BK;
        const ushort* Bgk = Bg + (size_t)(kt + 1)*BK;

        // ---- ph1: klo, nt0 ----
        #pragma unroll
        for (int mt = 0; mt < 4; ++mt) {
            af[mt*2+0] = *(const bf16x8*)&A0[rA + mt*1024 + kcA];
            af[mt*2+1] = *(const bf16x8*)&A0[rA + mt*1024 + kcB];
        }
        bf0 = *(const bf16x8*)&B0[rB + kcA];
        bf1 = *(const bf16x8*)&B0[rB + kcB];
        STAGE(nbuf, 0, Agk);
        SB(); BAR(); LGKM0(); SB();
        __builtin_amdgcn_s_setprio(1);
        MFMA8(0);
        __builtin_amdgcn_s_setprio(0);
        SB(); BAR(); SB();

        // ---- ph2: klo, nt1 ----
        bf0 = *(const bf16x8*)&B0[rB + 1024 + kcA];
        bf1 = *(const bf16x8*)&B0[rB + 1024 + kcB];
        STAGE(nbuf, 2, Bgk);
        SB(); BAR(); LGKM0(); SB();
        __builtin_amdgcn_s_setprio(1);
        MFMA8(1);
        __builtin_amdgcn_s_setprio(0);
        SB(); VM(4); BAR(); SB();

        // ---- ph3: khi, nt0 ----
        #pragma unroll
        for (int mt = 0; mt < 4; ++mt) {
            af[mt*2+0] = *(const bf16x8*)&A1[rA + mt*1024 + kcA];
            af[mt*2+1] = *(const bf16x8*)&A1[rA + mt*1024 + kcB];
        }
        bf0 = *(const bf16x8*)&B1[rB + kcA];
        bf1 = *(const bf16x8*)&B1[rB + kcB];
        STAGE(nbuf, 1, Agk + 32);
        SB(); BAR(); LGKM0(); SB();
        __builtin_amdgcn_s_setprio(1);
        MFMA8(0);
        __builtin_amdgcn_s_setprio(0);
        SB(); BAR(); SB();

        // ---- ph4: khi, nt1 ----
        bf0 = *(const bf16x8*)&B1[rB + 1024 + kcA];
        bf1 = *(const bf16x8*)&B1[rB + 1024 + kcB];
        STAGE(nbuf, 3, Bgk + 32);
        SB(); BAR(); LGKM0(); SB();
        __builtin_amdgcn_s_setprio(1);
        MFMA8(1);
        __builtin_amdgcn_s_setprio(0);
        SB(); VM(4); BAR(); SB();
    }

    // ---- last tile, peeled ----
    {
        const int buf = (TK - 1) & 1;
        const ushort* A0 = &L[buf][0][0];
        const ushort* A1 = &L[buf][1][0];
        const ushort* B0 = &L[buf][2][0];
        const ushort* B1 = &L[buf][3][0];

        #pragma unroll
        for (int mt = 0; mt < 4; ++mt) {
            af[mt*2+0] = *(const bf16x8*)&A0[rA + mt*1024 + kcA];
            af[mt*2+1] = *(const bf16x8*)&A0[rA + mt*1024 + kcB];
        }
        bf0 = *(const bf16x8*)&B0[rB + kcA];
        bf1 = *(const bf16x8*)&B0[rB + kcB];
        MFMA8(0);
        bf0 = *(const bf16x8*)&B0[rB + 1024 + kcA];
        bf1 = *(const bf16x8*)&B0[rB + 1024 + kcB];
        MFMA8(1);
        VM(0);
        BAR(); SB();
        #pragma unroll
        for (int mt = 0; mt < 4; ++mt) {
            af[mt*2+0] = *(const bf16x8*)&A1[rA + mt*1024 + kcA];
            af[mt*2+1] = *(const bf16x8*)&A1[rA + mt*1024 + kcB];
        }
        bf0 = *(const bf16x8*)&B1[rB + kcA];
        bf1 = *(const bf16x8*)&B1[rB + kcB];
        MFMA8(0);
        bf0 = *(const bf16x8*)&B1[rB + 1024 + kcA];
        bf1 = *(const bf16x8*)&B1[rB + 1024 + kcB];
        MFMA8(1);
    }
#undef MFMA8
#undef STAGE

    // epilogue: + bias + residual x  (32x32 C/D mapping)
    #pragma unroll
    for (int mt = 0; mt < 4; ++mt) {
        #pragma unroll
        for (int nt = 0; nt < 2; ++nt) {
            int col = hw0 + wc*64 + nt*32 + fr32;
            #pragma unroll
            for (int reg = 0; reg < 16; ++reg) {
                int ro = o0 + wr*128 + mt*32 + (reg & 3) + 8*(reg >> 2) + 4*kh;
                size_t idx = (size_t)b*NC*HWD + (size_t)ro*HWD + col;
                out[idx] = acc[mt][nt][reg] + bias[ro] + x[idx];
            }
        }
    }
}

extern "C" void kernel_launch(void* const* d_in, const int* in_sizes, int n_in,
                              void* d_out, int out_size, void* d_ws, size_t ws_size,
                              hipStream_t stream) {
    const float* x       = (const float*)d_in[0];
    const float* pos_dec = (const float*)d_in[1];
    const float* len_dec = (const float*)d_in[2];
    const float* conv_w  = (const float*)d_in[3];
    const float* conv_b  = (const float*)d_in[4];
    float* out = (float*)d_out;

    char* ws = (char*)d_ws;
    float*  part = (float*)ws;                    // 138,240 B
    float*  coef = part + PART_FLOATS;            // 1,920 B
    ushort* xT   = (ushort*)(ws + HEAD);          // 94,371,840 B (xT or featT)

    k_trans<<<dim3(CHP, BB), 256, 0, stream>>>(x, xT, part);
    k_coef <<<dim3(1), 256, 0, stream>>>(part, pos_dec, len_dec, coef);

    if (ws_size >= HEAD + XT_BYTES + W2_BYTES) {
        ushort* w2 = (ushort*)(ws + HEAD + XT_BYTES);   // 52,428,800 B
        k_w2  <<<dim3(800, BB), 256, 0, stream>>>(conv_w, coef, w2);
        k_gemm<<<dim3(720), 512, 0, stream>>>(w2, xT, conv_b, x, out, (size_t)NC*NC);
    } else {
        ushort* wb = (ushort*)(ws + HEAD + XT_BYTES);   // 3,276,800 B
        k_wconv<<<dim3(1600), 256, 0, stream>>>(conv_w, wb);
        k_feat <<<dim3(CHP, BB), 256, 0, stream>>>(x, coef, xT);
        k_gemm <<<dim3(720), 512, 0, stream>>>(wb, xT, conv_b, x, out, (size_t)0);
    }
}